// Round 8
// baseline (1865.921 us; speedup 1.0000x reference)
//
#include <hip/hip_runtime.h>
#include <stdint.h>

// FPS: B=32 batches, P=131072 points, S=512 samples.
// Round-8 layout: 32 batches x 16 groups, 1024 threads/wg, KPT=8 points/thread.
// EVERYTHING per-thread (points + running min-dists) in VGPRs: demand ~55 regs,
// __launch_bounds__(1024,8) pins the 64-reg budget => 2 wgs/CU, 8 waves/SIMD.
// No LDS in the update chain at all. Grid 512 = exactly-full co-residency.
// Per step: update -> two-phase DPP wave reduce -> lane0 stores tagged combo
// [distbits:32][tag:10][~idx:17] to LDS sk[parity][wave] -> barrier ->
//   wave0 only: gather 16 slots, DPP reduce, t0 publishes to the batch's
//   global 128B record line (relaxed agent; combo self-contained)
//   all waves: poll the 16 group records (lanes 0-15), DPP reduce, broadcast,
//   fetch winner coords from points[] (read-only => plain cached load safe).
// Overwrite safety: records parity-double-buffered; slot for step s+2 is only
// written after its writer passed the step-s+1 poll, which implies every
// reader of the step-s slot already finished. Tags 1..512 never repeat.

#define BATCHES 32
#define THREADS 1024
#define GROUPS  16
#define KPT     8             // P / (GROUPS*THREADS)
#define NWAVES  (THREADS / 64)
#define IDX_MASK 0x1FFFFu     // 17 bits: P=131072
#define TAG_SHIFT 22
#define TAG_MASK 0x3FFu       // tags 1..512; 0xAA-poison tag=682 never matches
#define LINE_U64 16           // 128B per (batch,parity) record line

// Full-wave (64-lane) max reduce in the VALU pipe (DPP). Result in lane 63;
// inputs must be u32 with 0 as a safe neutral (bound_ctrl:0 => OOB reads 0).
__device__ __forceinline__ uint32_t dpp_wave_max(uint32_t v) {
  uint32_t o;
  o = (uint32_t)__builtin_amdgcn_update_dpp(0, (int)v, 0x111, 0xf, 0xf, true); // row_shr:1
  v = o > v ? o : v;
  o = (uint32_t)__builtin_amdgcn_update_dpp(0, (int)v, 0x112, 0xf, 0xf, true); // row_shr:2
  v = o > v ? o : v;
  o = (uint32_t)__builtin_amdgcn_update_dpp(0, (int)v, 0x114, 0xf, 0xf, true); // row_shr:4
  v = o > v ? o : v;
  o = (uint32_t)__builtin_amdgcn_update_dpp(0, (int)v, 0x118, 0xf, 0xf, true); // row_shr:8
  v = o > v ? o : v;
  o = (uint32_t)__builtin_amdgcn_update_dpp(0, (int)v, 0x142, 0xa, 0xf, true); // row_bcast:15
  v = o > v ? o : v;
  o = (uint32_t)__builtin_amdgcn_update_dpp(0, (int)v, 0x143, 0xc, 0xf, true); // row_bcast:31
  v = o > v ? o : v;
  return v;   // lane 63 holds the wave max
}

__device__ __forceinline__ uint32_t wave_max_bcast(uint32_t v) {
  return (uint32_t)__builtin_amdgcn_readlane((int)dpp_wave_max(v), 63);
}

__global__ void init_ws_kernel(uint64_t* cand) {
  cand[threadIdx.x] = 0ull;   // BATCHES*2*LINE_U64 = 1024 exactly (tag=0)
}

__global__ __launch_bounds__(THREADS, 8)   // pin 64-VGPR budget (8 waves/EU)
void fps_kernel(const float* __restrict__ points,
                const int* __restrict__ nsamp_p,
                float* __restrict__ out,
                uint64_t* __restrict__ cand,
                int P) {
#pragma clang fp contract(off)
  // Swizzle: all 16 groups of a batch share an XCD (l%8 == b%8 heuristic).
  const int l = blockIdx.x;               // 0..511
  const int b = (l & 7) + (((l >> 3) & 3) << 3);   // batch 0..31
  const int g = l >> 5;                   // group 0..15
  const int t = threadIdx.x;
  const int lane = t & 63;
  const int w = t >> 6;
  const int S = nsamp_p[0];
  const int base = g * (P / GROUPS);      // 8192 per group
  const float* pb = points + (size_t)b * P * 3;

  __shared__ uint64_t sk[2][NWAVES];      // self-tagged wave combos (256B)

  // This thread's 8 points + running min-dists, all in VGPRs (~55 regs).
  float px[KPT], py[KPT], pz[KPT], dist[KPT];
#pragma unroll
  for (int k = 0; k < KPT; ++k) {
    int p = base + t + k * THREADS;
    px[k] = pb[(size_t)p * 3 + 0];
    py[k] = pb[(size_t)p * 3 + 1];
    pz[k] = pb[(size_t)p * 3 + 2];
    dist[k] = __builtin_inff();
  }

  // Wave-carried current state (wave-uniform registers).
  int cur = 0;                 // reference always starts at index 0
  float cx = pb[0], cy = pb[1], cz = pb[2];

  float* out_idx = out;                        // [B][S] indices as f32
  float* out_pts = out + (size_t)BATCHES * S;  // [B][S][3]
  uint64_t* line_base = cand + (size_t)b * 2 * LINE_U64;

  for (int s = 0; s < S; ++s) {
    const uint32_t tag = (uint32_t)(s + 1);
    const int par = s & 1;

    // ---- update running min-dists; per-thread (max dist, first index) ----
    float bd = -1.0f;
    int bi = 0;
#pragma unroll
    for (int k = 0; k < KPT; ++k) {
      float dx = px[k] - cx;
      float dy = py[k] - cy;
      float dz = pz[k] - cz;
      float d = (dx * dx + dy * dy) + dz * dz;   // numpy order, no FMA
      float nd = dist[k] < d ? dist[k] : d;      // jnp.minimum
      dist[k] = nd;
      if (nd > bd) { bd = nd; bi = base + t + k * THREADS; }  // k asc => first-max
    }

    // ---- two-phase wave reduce via DPP: max distbits, then max ~idx ----
    const uint32_t mydb = __float_as_uint(bd);   // bd >= 0 => order-preserving
    const uint32_t db = wave_max_bcast(mydb);
    const uint32_t mk = wave_max_bcast((mydb == db) ? ~(uint32_t)bi : 0u);

    if (lane == 0) {
      sk[par][w] = ((unsigned long long)db << 32) |
                   ((unsigned long long)tag << TAG_SHIFT) |
                   (unsigned long long)(mk & IDX_MASK);
    }
    __syncthreads();   // the only barrier per step

    uint64_t* line = line_base + (size_t)par * LINE_U64;

    if (w == 0) {
      // wave0 only: reduce the 16 wave combos, publish the group record.
      unsigned long long sv = (lane < NWAVES) ? sk[par][lane] : 0ull;
      uint32_t ghi = (uint32_t)(sv >> 32);
      const uint32_t gdb = wave_max_bcast(ghi);
      const uint32_t gmk = wave_max_bcast((lane < NWAVES && ghi == gdb)
                                          ? ((uint32_t)sv & IDX_MASK) : 0u);
      if (lane == 0) {
        unsigned long long combo = ((unsigned long long)gdb << 32) |
                                   ((unsigned long long)tag << TAG_SHIFT) |
                                   (unsigned long long)gmk;
        __hip_atomic_store(&line[g], combo, __ATOMIC_RELAXED,
                           __HIP_MEMORY_SCOPE_AGENT);
        if (g == 0) {   // off the critical path (after publish)
          out_idx[(size_t)b * S + s] = (float)cur;
          size_t o = ((size_t)b * S + s) * 3;
          out_pts[o + 0] = cx; out_pts[o + 1] = cy; out_pts[o + 2] = cz;
        }
      }
    }

    // ---- all waves poll the 16 group records (relaxed, self-contained) ----
    unsigned long long v = 0;
    int done = (lane < GROUPS) ? 0 : 1;
    while (!__all(done)) {
      if (!done) {
        v = __hip_atomic_load(&line[lane], __ATOMIC_RELAXED,
                              __HIP_MEMORY_SCOPE_AGENT);
        done = (((uint32_t)(v >> TAG_SHIFT) & TAG_MASK) == tag);
      }
      if (!__all(done)) __builtin_amdgcn_s_sleep(1);
    }
    uint32_t fhi = (uint32_t)(v >> 32);
    const uint32_t fdb = wave_max_bcast(fhi);
    const uint32_t fmk = wave_max_bcast((fhi == fdb) ? ((uint32_t)v & IDX_MASK) : 0u);

    // ---- winner index + coords (read-only data: plain cached load safe) ----
    cur = (int)((~fmk) & IDX_MASK);
    const float* wp = pb + (size_t)cur * 3;
    cx = wp[0]; cy = wp[1]; cz = wp[2];
  }
}

extern "C" void kernel_launch(void* const* d_in, const int* in_sizes, int n_in,
                              void* d_out, int out_size, void* d_ws, size_t ws_size,
                              hipStream_t stream) {
  const float* points = (const float*)d_in[0];
  const int* nsamples = (const int*)d_in[1];
  // d_in[2] = kd_depth: acceleration parameter only; math identical. Ignored.

  const int P = in_sizes[0] / (BATCHES * 3);   // 131072

  uint64_t* cand = (uint64_t*)d_ws;   // [32][2][16 u64] = 8KB

  hipLaunchKernelGGL(init_ws_kernel, dim3(1), dim3(BATCHES * 2 * LINE_U64),
                     0, stream, cand);

  dim3 grid(GROUPS * BATCHES);        // 512 wgs = 2/CU, exactly co-resident
  hipLaunchKernelGGL(fps_kernel, grid, dim3(THREADS), 0, stream,
                     points, nsamples, (float*)d_out, cand, P);
}

// Round 10
// 1818.948 us; speedup vs baseline: 1.0258x; 1.0258x over previous
//
#include <hip/hip_runtime.h>
#include <stdint.h>

// FPS: B=32 batches, P=131072 points, S=512 samples.
// Round-10 (= round-9 resubmit; r9 died to container infra, audit found no
// deadlock path): 32 batches x 16 groups, 512 threads/wg, KPT=16.
// Per-thread structure = round-7 verified (48 coord VGPRs, dists in LDS
// thread-private slots, ~56 regs, no spill). Grid 512 wgs => 2 wgs/CU:
// one wg's VALU work overlaps the other wg's barrier/publish/poll stalls
// (r7 had 1 wg/CU; VALUBusy 63% => ~0.5ms of unoverlapped sync stall).
// Capacity audit: LDS 32.25KB (4/CU), waves_per_eu(4,4) => 16 waves/CU =
// exactly 2 wgs and forces <=128-VGPR allocation; 512 wgs fill 512 slots.
// Protocol (verified r5-r7): per step, two-phase DPP wave reduce ->
// lane0 stores self-tagged combo [distbits:32][tag:10][~idx:17] to LDS
// sk[parity][wave] -> one __syncthreads -> wave0 reduces 8 slots, t0
// publishes to the batch's global 128B record line (relaxed agent-scope;
// combo self-contained) -> all waves poll the 16 group slots (lanes 0-15),
// DPP reduce, readlane-broadcast -> scalar-path winner-coord fetch.
// Overwrite safety: records parity-double-buffered; a slot for step s+2 is
// written only after its writer passed the step-s+1 poll, which implies all
// readers of the step-s slot finished. Tags 1..512 never repeat per slot;
// 0xAA poison decodes to tag 682 (never matches).

#define BATCHES 32
#define THREADS 512
#define GROUPS  16
#define KPT     16            // P / (GROUPS*THREADS)
#define NWAVES  (THREADS / 64)
#define IDX_MASK 0x1FFFFu     // 17 bits: P=131072
#define TAG_SHIFT 22
#define TAG_MASK 0x3FFu
#define LINE_U64 16           // 128B per (batch,parity) record line

// Full-wave (64-lane) max reduce in the VALU pipe (DPP). Result in lane 63;
// inputs u32 with 0 as safe neutral (bound_ctrl:0 => OOB reads 0).
__device__ __forceinline__ uint32_t dpp_wave_max(uint32_t v) {
  uint32_t o;
  o = (uint32_t)__builtin_amdgcn_update_dpp(0, (int)v, 0x111, 0xf, 0xf, true); // row_shr:1
  v = o > v ? o : v;
  o = (uint32_t)__builtin_amdgcn_update_dpp(0, (int)v, 0x112, 0xf, 0xf, true); // row_shr:2
  v = o > v ? o : v;
  o = (uint32_t)__builtin_amdgcn_update_dpp(0, (int)v, 0x114, 0xf, 0xf, true); // row_shr:4
  v = o > v ? o : v;
  o = (uint32_t)__builtin_amdgcn_update_dpp(0, (int)v, 0x118, 0xf, 0xf, true); // row_shr:8
  v = o > v ? o : v;
  o = (uint32_t)__builtin_amdgcn_update_dpp(0, (int)v, 0x142, 0xa, 0xf, true); // row_bcast:15
  v = o > v ? o : v;
  o = (uint32_t)__builtin_amdgcn_update_dpp(0, (int)v, 0x143, 0xc, 0xf, true); // row_bcast:31
  v = o > v ? o : v;
  return v;   // lane 63 holds the wave max
}

__device__ __forceinline__ uint32_t wave_max_bcast(uint32_t v) {
  return (uint32_t)__builtin_amdgcn_readlane((int)dpp_wave_max(v), 63);
}

__global__ void init_ws_kernel(uint64_t* cand) {
  cand[threadIdx.x] = 0ull;   // BATCHES*2*LINE_U64 = 1024 exactly (tag=0)
}

__global__ __attribute__((amdgpu_flat_work_group_size(THREADS, THREADS),
                          amdgpu_waves_per_eu(4, 4)))
void fps_kernel(const float* __restrict__ points,
                const int* __restrict__ nsamp_p,
                float* __restrict__ out,
                uint64_t* __restrict__ cand,
                int P) {
#pragma clang fp contract(off)
  // Swizzle: all 16 groups of a batch share an XCD (l%8 == b%8 heuristic).
  const int l = blockIdx.x;               // 0..511
  const int b = (l & 7) + (((l >> 3) & 3) << 3);   // batch 0..31
  const int g = l >> 5;                   // group 0..15
  const int t = threadIdx.x;
  const int lane = t & 63;
  const int w = t >> 6;
  const int S = nsamp_p[0];
  const int base = g * (P / GROUPS);      // 8192 points per group
  const float* pb = points + (size_t)b * P * 3;

  __shared__ float sdist[KPT * THREADS];  // 32KB; thread-private slots
  __shared__ uint64_t sk[2][NWAVES];      // self-tagged wave combos

  // This thread's 16 points into VGPRs; dists to LDS (+inf).
  float px[KPT], py[KPT], pz[KPT];
#pragma unroll
  for (int k = 0; k < KPT; ++k) {
    int p = base + t + k * THREADS;
    px[k] = pb[(size_t)p * 3 + 0];
    py[k] = pb[(size_t)p * 3 + 1];
    pz[k] = pb[(size_t)p * 3 + 2];
    sdist[k * THREADS + t] = __builtin_inff();
  }

  // Wave-carried current state (wave-uniform registers).
  int cur = 0;                 // reference always starts at index 0
  float cx = pb[0], cy = pb[1], cz = pb[2];

  float* out_idx = out;                        // [B][S] indices as f32
  float* out_pts = out + (size_t)BATCHES * S;  // [B][S][3]
  uint64_t* line_base = cand + (size_t)b * 2 * LINE_U64;

  for (int s = 0; s < S; ++s) {
    const uint32_t tag = (uint32_t)(s + 1);
    const int par = s & 1;

    // ---- update running min-dists; per-thread (max dist, first index) ----
    float bd = -1.0f;
    int bi = 0;
#pragma unroll
    for (int k = 0; k < KPT; ++k) {
      float dx = px[k] - cx;
      float dy = py[k] - cy;
      float dz = pz[k] - cz;
      float d = (dx * dx + dy * dy) + dz * dz;   // numpy order, no FMA
      float od = sdist[k * THREADS + t];
      float nd = od < d ? od : d;                // jnp.minimum
      sdist[k * THREADS + t] = nd;
      if (nd > bd) { bd = nd; bi = base + t + k * THREADS; }  // k asc => first-max
    }

    // ---- two-phase wave reduce via DPP: max distbits, then max ~idx ----
    const uint32_t mydb = __float_as_uint(bd);   // bd >= 0 => order-preserving
    const uint32_t db = wave_max_bcast(mydb);
    const uint32_t mk = wave_max_bcast((mydb == db) ? ~(uint32_t)bi : 0u);

    if (lane == 0) {
      sk[par][w] = ((unsigned long long)db << 32) |
                   ((unsigned long long)tag << TAG_SHIFT) |
                   (unsigned long long)(mk & IDX_MASK);
    }
    __syncthreads();   // the only barrier per step (8 waves)

    uint64_t* line = line_base + (size_t)par * LINE_U64;

    if (w == 0) {
      // wave0 only: reduce the 8 wave combos, publish the group record.
      unsigned long long sv = (lane < NWAVES) ? sk[par][lane] : 0ull;
      uint32_t ghi = (uint32_t)(sv >> 32);
      const uint32_t gdb = wave_max_bcast(ghi);
      const uint32_t gmk = wave_max_bcast((lane < NWAVES && ghi == gdb)
                                          ? ((uint32_t)sv & IDX_MASK) : 0u);
      if (lane == 0) {
        unsigned long long combo = ((unsigned long long)gdb << 32) |
                                   ((unsigned long long)tag << TAG_SHIFT) |
                                   (unsigned long long)gmk;
        __hip_atomic_store(&line[g], combo, __ATOMIC_RELAXED,
                           __HIP_MEMORY_SCOPE_AGENT);
        if (g == 0) {   // off the critical path (after publish)
          out_idx[(size_t)b * S + s] = (float)cur;
          size_t o = ((size_t)b * S + s) * 3;
          out_pts[o + 0] = cx; out_pts[o + 1] = cy; out_pts[o + 2] = cz;
        }
      }
    }

    // ---- all waves poll the 16 group records (relaxed, self-contained) ----
    unsigned long long v = 0;
    int done = (lane < GROUPS) ? 0 : 1;
    while (!__all(done)) {
      if (!done) {
        v = __hip_atomic_load(&line[lane], __ATOMIC_RELAXED,
                              __HIP_MEMORY_SCOPE_AGENT);
        done = (((uint32_t)(v >> TAG_SHIFT) & TAG_MASK) == tag);
      }
      if (!__all(done)) __builtin_amdgcn_s_sleep(1);
    }
    uint32_t fhi = (uint32_t)(v >> 32);
    const uint32_t fdb = wave_max_bcast(fhi);
    const uint32_t fmk = wave_max_bcast((fhi == fdb) ? ((uint32_t)v & IDX_MASK) : 0u);

    // ---- winner index + coords (scalar-path uniform load) ----
    cur = __builtin_amdgcn_readfirstlane((int)((~fmk) & IDX_MASK));
    const float* wp = pb + (size_t)cur * 3;
    cx = wp[0]; cy = wp[1]; cz = wp[2];
  }
}

extern "C" void kernel_launch(void* const* d_in, const int* in_sizes, int n_in,
                              void* d_out, int out_size, void* d_ws, size_t ws_size,
                              hipStream_t stream) {
  const float* points = (const float*)d_in[0];
  const int* nsamples = (const int*)d_in[1];
  // d_in[2] = kd_depth: acceleration parameter only; math identical. Ignored.

  const int P = in_sizes[0] / (BATCHES * 3);   // 131072

  uint64_t* cand = (uint64_t*)d_ws;   // [32][2][16 u64] = 8KB

  hipLaunchKernelGGL(init_ws_kernel, dim3(1), dim3(BATCHES * 2 * LINE_U64),
                     0, stream, cand);

  hipLaunchKernelGGL(fps_kernel, dim3(GROUPS * BATCHES), dim3(THREADS), 0,
                     stream, points, nsamples, (float*)d_out, cand, P);
}

// Round 11
// 1633.290 us; speedup vs baseline: 1.1424x; 1.1137x over previous
//
#include <hip/hip_runtime.h>
#include <stdint.h>

// FPS: B=32 batches, P=131072 points, S=512 samples.
// Round-11: TWO independent batch-chains per workgroup, software-pipelined to
// hide the inter-WG fan-in latency inside the instruction stream.
// 256 wgs x 1024 threads (1 wg/CU). wg <-> (group g of 16, batches bA, bA+16).
// KPT=8 per chain (16 pts/thread total = r7's update work). Coords in VGPRs
// (48), dists for both chains in LDS thread-private slots (64KB).
// Per iter s: [pollA(tag s) -> fetchA -> updateA -> DPP reduce -> store skA;
//             barrier; wave0: reduce 16 skA + publish A-record(tag s+1)]
//             then the same for chain B. Chain A's publish->poll gap is
//             covered by B's phase and vice versa (symmetric half-iter slack).
// Global records: verified r5-r7 protocol -- self-contained 8B combo
// [distbits:32][tag:10][~idx:17], relaxed agent-scope, parity-double-buffered
// line of 16 slots (128B) per batch. Overwrite safety: a record for tag s+2
// is stored only after its wg passed poll(tag s+1), which implies every
// reader of the tag-s record finished. skA/skB LDS slots need no parity:
// wave w re-stores sk only after passing poll(s+1), which requires own
// wave0's publish, which follows wave0's read of sk.
// Winner coords fetched via readfirstlane -> scalar (SGPR) loads.

#define BATCHES 32
#define THREADS 1024
#define GROUPS  16
#define KPT     8             // per chain; P/(GROUPS*THREADS)
#define NWAVES  (THREADS / 64)
#define IDX_MASK 0x1FFFFu     // 17 bits: P=131072
#define TAG_SHIFT 22
#define TAG_MASK 0x3FFu       // tags 1..512; 0xAA poison tag=682 never matches
#define LINE_U64 16           // 128B per (batch,parity) record line

// Full-wave (64-lane) max reduce in the VALU pipe (DPP). Result in lane 63;
// inputs u32 with 0 as safe neutral (bound_ctrl:0 => OOB reads 0).
__device__ __forceinline__ uint32_t dpp_wave_max(uint32_t v) {
  uint32_t o;
  o = (uint32_t)__builtin_amdgcn_update_dpp(0, (int)v, 0x111, 0xf, 0xf, true); // row_shr:1
  v = o > v ? o : v;
  o = (uint32_t)__builtin_amdgcn_update_dpp(0, (int)v, 0x112, 0xf, 0xf, true); // row_shr:2
  v = o > v ? o : v;
  o = (uint32_t)__builtin_amdgcn_update_dpp(0, (int)v, 0x114, 0xf, 0xf, true); // row_shr:4
  v = o > v ? o : v;
  o = (uint32_t)__builtin_amdgcn_update_dpp(0, (int)v, 0x118, 0xf, 0xf, true); // row_shr:8
  v = o > v ? o : v;
  o = (uint32_t)__builtin_amdgcn_update_dpp(0, (int)v, 0x142, 0xa, 0xf, true); // row_bcast:15
  v = o > v ? o : v;
  o = (uint32_t)__builtin_amdgcn_update_dpp(0, (int)v, 0x143, 0xc, 0xf, true); // row_bcast:31
  v = o > v ? o : v;
  return v;   // lane 63 holds the wave max
}

__device__ __forceinline__ uint32_t wave_max_bcast(uint32_t v) {
  return (uint32_t)__builtin_amdgcn_readlane((int)dpp_wave_max(v), 63);
}

__global__ void init_ws_kernel(uint64_t* cand) {
  cand[threadIdx.x] = 0ull;   // BATCHES*2*LINE_U64 = 1024 exactly (tag=0)
}

// One chain-phase: poll winner of step s (skip at s==0), fetch coords,
// write outputs (g==0), update dists, wave-reduce, store wave combo to LDS.
__device__ __forceinline__ void fps_phase(
    int s, int S, const float* __restrict__ pb,
    float* __restrict__ sdistC, uint64_t* __restrict__ skC,
    uint64_t* __restrict__ lineBase,
    const float* px, const float* py, const float* pz,
    int base, int t, int lane, int w, int g, int b,
    int& cur, float* __restrict__ out_idx, float* __restrict__ out_pts) {
#pragma clang fp contract(off)
  if (s > 0) {
    uint64_t* line = lineBase + (size_t)(s & 1) * LINE_U64;
    unsigned long long v = 0;
    int done = (lane < GROUPS) ? 0 : 1;
    while (!__all(done)) {
      if (!done) {
        v = __hip_atomic_load(&line[lane], __ATOMIC_RELAXED,
                              __HIP_MEMORY_SCOPE_AGENT);
        done = (((uint32_t)(v >> TAG_SHIFT) & TAG_MASK) == (uint32_t)s);
      }
      if (!__all(done)) __builtin_amdgcn_s_sleep(1);
    }
    uint32_t fhi = (uint32_t)(v >> 32);
    const uint32_t fdb = wave_max_bcast(fhi);
    const uint32_t fmk = wave_max_bcast((fhi == fdb) ? ((uint32_t)v & IDX_MASK) : 0u);
    cur = __builtin_amdgcn_readfirstlane((int)((~fmk) & IDX_MASK));
  }
  // coords: cur is wave-uniform (readfirstlane) => scalar loads, SGPR coords
  const float cx = pb[(size_t)cur * 3 + 0];
  const float cy = pb[(size_t)cur * 3 + 1];
  const float cz = pb[(size_t)cur * 3 + 2];
  if (g == 0 && t == 0) {
    out_idx[(size_t)b * S + s] = (float)cur;
    size_t o = ((size_t)b * S + s) * 3;
    out_pts[o + 0] = cx; out_pts[o + 1] = cy; out_pts[o + 2] = cz;
  }
  // update running min-dists; per-thread (max dist, first index)
  float bd = -1.0f;
  int bi = 0;
#pragma unroll
  for (int k = 0; k < KPT; ++k) {
    float dx = px[k] - cx;
    float dy = py[k] - cy;
    float dz = pz[k] - cz;
    float d = (dx * dx + dy * dy) + dz * dz;   // numpy order, no FMA
    float od = sdistC[k * THREADS + t];
    float nd = od < d ? od : d;                // jnp.minimum
    sdistC[k * THREADS + t] = nd;
    if (nd > bd) { bd = nd; bi = base + t + k * THREADS; }  // k asc => first-max
  }
  // two-phase DPP wave reduce: max distbits, then max ~idx among tied
  const uint32_t mydb = __float_as_uint(bd);   // bd >= 0 => order-preserving
  const uint32_t db = wave_max_bcast(mydb);
  const uint32_t mk = wave_max_bcast((mydb == db) ? ~(uint32_t)bi : 0u);
  if (lane == 0) {
    skC[w] = ((unsigned long long)db << 32) |
             ((unsigned long long)(uint32_t)(s + 1) << TAG_SHIFT) |
             (unsigned long long)(mk & IDX_MASK);
  }
}

// wave0: reduce the 16 wave combos of one chain, publish the group record.
__device__ __forceinline__ void fps_publish(
    const uint64_t* __restrict__ skC, uint64_t* __restrict__ slotLine,
    int lane, int g) {
  unsigned long long sv = (lane < NWAVES) ? skC[lane] : 0ull;
  uint32_t hi = (uint32_t)(sv >> 32);
  const uint32_t gdb = wave_max_bcast(hi);
  const uint32_t gmk = wave_max_bcast((lane < NWAVES && hi == gdb)
                                      ? ((uint32_t)sv & IDX_MASK) : 0u);
  // tag rides in through sv (all slots carry identical tag); rebuild combo
  const uint32_t tagbits = (uint32_t)(skC[0] >> 32 == 0 ? 0 : 0); // unused
  (void)tagbits;
  if (lane == 0) {
    const unsigned long long tagfield =
        skC[0] & ((unsigned long long)TAG_MASK << TAG_SHIFT);
    unsigned long long combo = ((unsigned long long)gdb << 32) |
                               tagfield |
                               (unsigned long long)gmk;
    __hip_atomic_store(slotLine + g, combo, __ATOMIC_RELAXED,
                       __HIP_MEMORY_SCOPE_AGENT);
  }
}

__global__ __attribute__((amdgpu_flat_work_group_size(THREADS, THREADS)))
void fps_kernel(const float* __restrict__ points,
                const int* __restrict__ nsamp_p,
                float* __restrict__ out,
                uint64_t* __restrict__ cand,
                int P) {
#pragma clang fp contract(off)
  // 256 wgs: l -> (bA in 0..15, g in 0..15); chain B batch = bA+16.
  // l%8 == bA%8 => all 16 groups of both batches share an XCD (heuristic).
  const int l = blockIdx.x;                      // 0..255
  const int bA = (l & 7) | (((l >> 3) & 1) << 3);  // 0..15
  const int bB = bA + 16;
  const int g = l >> 4;                          // 0..15
  const int t = threadIdx.x;
  const int lane = t & 63;
  const int w = t >> 6;
  const int S = nsamp_p[0];
  const int base = g * (P / GROUPS);             // 8192 points per group
  const float* pbA = points + (size_t)bA * P * 3;
  const float* pbB = points + (size_t)bB * P * 3;

  __shared__ float sdist[2 * KPT * THREADS];     // 64KB, thread-private slots
  __shared__ uint64_t skA[NWAVES], skB[NWAVES];  // wave combos (barrier-protected)

  float* sdistA = sdist;
  float* sdistB = sdist + KPT * THREADS;

  // Load both chains' points into VGPRs; dists to LDS (+inf).
  float pxA[KPT], pyA[KPT], pzA[KPT], pxB[KPT], pyB[KPT], pzB[KPT];
#pragma unroll
  for (int k = 0; k < KPT; ++k) {
    int p = base + t + k * THREADS;
    pxA[k] = pbA[(size_t)p * 3 + 0];
    pyA[k] = pbA[(size_t)p * 3 + 1];
    pzA[k] = pbA[(size_t)p * 3 + 2];
    pxB[k] = pbB[(size_t)p * 3 + 0];
    pyB[k] = pbB[(size_t)p * 3 + 1];
    pzB[k] = pbB[(size_t)p * 3 + 2];
    sdistA[k * THREADS + t] = __builtin_inff();
    sdistB[k * THREADS + t] = __builtin_inff();
  }

  int curA = 0, curB = 0;      // reference always starts at index 0
  float* out_idx = out;                        // [B][S] indices as f32
  float* out_pts = out + (size_t)BATCHES * S;  // [B][S][3]
  uint64_t* lineA = cand + (size_t)bA * 2 * LINE_U64;
  uint64_t* lineB = cand + (size_t)bB * 2 * LINE_U64;

  for (int s = 0; s < S; ++s) {
    const int parNext = (s + 1) & 1;
    // ---- chain A phase: poll(s) -> fetch -> update -> reduce -> store sk ----
    fps_phase(s, S, pbA, sdistA, skA, lineA, pxA, pyA, pzA,
              base, t, lane, w, g, bA, curA, out_idx, out_pts);
    __syncthreads();
    if (w == 0)
      fps_publish(skA, lineA + (size_t)parNext * LINE_U64, lane, g);
    // ---- chain B phase (covers A's publish->poll latency) ----
    fps_phase(s, S, pbB, sdistB, skB, lineB, pxB, pyB, pzB,
              base, t, lane, w, g, bB, curB, out_idx, out_pts);
    __syncthreads();
    if (w == 0)
      fps_publish(skB, lineB + (size_t)parNext * LINE_U64, lane, g);
    // loop wraps: A's poll(s+1) is covered by B's phase above; B's poll(s+1)
    // is covered by A's phase of the next iteration.
  }
}

extern "C" void kernel_launch(void* const* d_in, const int* in_sizes, int n_in,
                              void* d_out, int out_size, void* d_ws, size_t ws_size,
                              hipStream_t stream) {
  const float* points = (const float*)d_in[0];
  const int* nsamples = (const int*)d_in[1];
  // d_in[2] = kd_depth: acceleration parameter only; math identical. Ignored.

  const int P = in_sizes[0] / (BATCHES * 3);   // 131072

  uint64_t* cand = (uint64_t*)d_ws;   // [32][2][16 u64] = 8KB

  hipLaunchKernelGGL(init_ws_kernel, dim3(1), dim3(BATCHES * 2 * LINE_U64),
                     0, stream, cand);

  hipLaunchKernelGGL(fps_kernel, dim3(GROUPS * (BATCHES / 2)), dim3(THREADS),
                     0, stream, points, nsamples, (float*)d_out, cand, P);
}

// Round 13
// 1291.579 us; speedup vs baseline: 1.4447x; 1.2646x over previous
//
#include <hip/hip_runtime.h>
#include <stdint.h>

// FPS: B=32 batches, P=131072 points, S=512 samples.
// Round-13 (= round-12 resubmit; r12 died to the same container-infra error
// as r9, which proved spurious on resubmit. Audit: no deadlock path --
// 8 waves/wg x 256 wgs = 2048 waves, <=256 VGPR => 2 waves/SIMD => exactly
// 1 wg/CU, all co-resident. One change vs r12: s_sleep(1) restored in the
// global poll, matching the r7-verified loop exactly.)
// Design: fan-in stays 8 (every GROUPS=16 variant lost), and the update
// chain goes pure-VALU: 512 threads/wg, KPT=32, points AND dists all in
// VGPRs (~150 regs; waves_per_eu(2,2) => 256-reg budget, 2 waves/SIMD,
// 1 wg/CU, grid 256 = full chip).
// Protocol = r7-verified: per step, two-phase DPP wave reduce -> lane0 stores
// self-tagged combo [distbits:32][tag:10][~idx:17] to LDS sk[parity][wave]
// -> one __syncthreads (8 waves) -> every wave reduces the 8 slots, t0
// publishes to the batch's global 128B record line (relaxed agent-scope;
// combo self-contained) -> all waves poll the 8 group slots (lanes 0-7,
// relaxed), DPP reduce, readfirstlane -> scalar winner-coord fetch.
// Overwrite safety: records parity-double-buffered; a record for step s+2 is
// stored only after its writer passed the step-s+1 poll, which implies every
// reader of the step-s record finished. Tags 1..512 never repeat per slot;
// 0xAA poison decodes to tag 682 (never matches).

#define BATCHES 32
#define THREADS 512
#define GROUPS  8
#define KPT     32            // P / (GROUPS*THREADS)
#define NWAVES  (THREADS / 64)
#define IDX_MASK 0x1FFFFu     // 17 bits: P=131072
#define TAG_SHIFT 22
#define TAG_MASK 0x3FFu
#define LINE_U64 16           // 128B per (batch,parity) record line

// Full-wave (64-lane) max reduce in the VALU pipe (DPP). Result in lane 63;
// inputs u32 with 0 as safe neutral (bound_ctrl:0 => OOB reads 0).
__device__ __forceinline__ uint32_t dpp_wave_max(uint32_t v) {
  uint32_t o;
  o = (uint32_t)__builtin_amdgcn_update_dpp(0, (int)v, 0x111, 0xf, 0xf, true); // row_shr:1
  v = o > v ? o : v;
  o = (uint32_t)__builtin_amdgcn_update_dpp(0, (int)v, 0x112, 0xf, 0xf, true); // row_shr:2
  v = o > v ? o : v;
  o = (uint32_t)__builtin_amdgcn_update_dpp(0, (int)v, 0x114, 0xf, 0xf, true); // row_shr:4
  v = o > v ? o : v;
  o = (uint32_t)__builtin_amdgcn_update_dpp(0, (int)v, 0x118, 0xf, 0xf, true); // row_shr:8
  v = o > v ? o : v;
  o = (uint32_t)__builtin_amdgcn_update_dpp(0, (int)v, 0x142, 0xa, 0xf, true); // row_bcast:15
  v = o > v ? o : v;
  o = (uint32_t)__builtin_amdgcn_update_dpp(0, (int)v, 0x143, 0xc, 0xf, true); // row_bcast:31
  v = o > v ? o : v;
  return v;   // lane 63 holds the wave max
}

__device__ __forceinline__ uint32_t wave_max_bcast(uint32_t v) {
  return (uint32_t)__builtin_amdgcn_readlane((int)dpp_wave_max(v), 63);
}

__global__ void init_ws_kernel(uint64_t* cand) {
  cand[threadIdx.x] = 0ull;   // BATCHES*2*LINE_U64 = 1024 exactly (tag=0)
}

__global__ __attribute__((amdgpu_flat_work_group_size(THREADS, THREADS),
                          amdgpu_waves_per_eu(2, 2)))
void fps_kernel(const float* __restrict__ points,
                const int* __restrict__ nsamp_p,
                float* __restrict__ out,
                uint64_t* __restrict__ cand,
                int P) {
#pragma clang fp contract(off)
  // Swizzle: all 8 groups of a batch share an XCD (l%8 == b%8 heuristic).
  const int l = blockIdx.x;               // 0..255
  const int b = (l & 7) + (((l >> 3) & 3) << 3);   // batch 0..31
  const int g = l >> 5;                   // group 0..7
  const int t = threadIdx.x;
  const int lane = t & 63;
  const int w = t >> 6;
  const int S = nsamp_p[0];
  const int base = g * (P / GROUPS);      // 16384 points per group
  const float* pb = points + (size_t)b * P * 3;

  __shared__ uint64_t sk[2][NWAVES];      // self-tagged wave combos (128B)

  // This thread's 32 points + running min-dists, ALL in VGPRs (~150 regs).
  float px[KPT], py[KPT], pz[KPT], dist[KPT];
#pragma unroll
  for (int k = 0; k < KPT; ++k) {
    int p = base + t + k * THREADS;
    px[k] = pb[(size_t)p * 3 + 0];
    py[k] = pb[(size_t)p * 3 + 1];
    pz[k] = pb[(size_t)p * 3 + 2];
    dist[k] = __builtin_inff();
  }

  // Wave-carried current state (wave-uniform; coords come from scalar loads).
  int cur = 0;                 // reference always starts at index 0
  float cx = pb[0], cy = pb[1], cz = pb[2];

  float* out_idx = out;                        // [B][S] indices as f32
  float* out_pts = out + (size_t)BATCHES * S;  // [B][S][3]
  uint64_t* line_base = cand + (size_t)b * 2 * LINE_U64;

  for (int s = 0; s < S; ++s) {
    const uint32_t tag = (uint32_t)(s + 1);
    const int par = s & 1;

    // ---- update running min-dists; per-thread (max dist, first index) ----
    float bd = -1.0f;
    int bi = 0;
#pragma unroll
    for (int k = 0; k < KPT; ++k) {
      float dx = px[k] - cx;
      float dy = py[k] - cy;
      float dz = pz[k] - cz;
      float d = (dx * dx + dy * dy) + dz * dz;   // numpy order, no FMA
      float nd = dist[k] < d ? dist[k] : d;      // jnp.minimum
      dist[k] = nd;
      if (nd > bd) { bd = nd; bi = base + t + k * THREADS; }  // k asc => first-max
    }

    // ---- two-phase wave reduce via DPP: max distbits, then max ~idx ----
    const uint32_t mydb = __float_as_uint(bd);   // bd >= 0 => order-preserving
    const uint32_t db = wave_max_bcast(mydb);
    const uint32_t mk = wave_max_bcast((mydb == db) ? ~(uint32_t)bi : 0u);

    if (lane == 0) {
      sk[par][w] = ((unsigned long long)db << 32) |
                   ((unsigned long long)tag << TAG_SHIFT) |
                   (unsigned long long)(mk & IDX_MASK);
    }
    __syncthreads();   // the only barrier per step (8 waves)

    // ---- every wave: reduce the 8 wave combos, t0 publishes ----
    unsigned long long sv = (lane < NWAVES) ? sk[par][lane] : 0ull;
    uint32_t ghi = (uint32_t)(sv >> 32);
    const uint32_t gdb = wave_max_bcast(ghi);
    const uint32_t gmk = wave_max_bcast((lane < NWAVES && ghi == gdb)
                                        ? ((uint32_t)sv & IDX_MASK) : 0u);

    uint64_t* line = line_base + (size_t)par * LINE_U64;
    if (t == 0) {
      unsigned long long combo = ((unsigned long long)gdb << 32) |
                                 ((unsigned long long)tag << TAG_SHIFT) |
                                 (unsigned long long)gmk;
      __hip_atomic_store(&line[g], combo, __ATOMIC_RELAXED,
                         __HIP_MEMORY_SCOPE_AGENT);
    }
    if (g == 0 && t == 0) {    // off the critical path (after publish)
      out_idx[(size_t)b * S + s] = (float)cur;
      size_t o = ((size_t)b * S + s) * 3;
      out_pts[o + 0] = cx; out_pts[o + 1] = cy; out_pts[o + 2] = cz;
    }

    // ---- all waves poll the 8 group records (relaxed, self-contained) ----
    unsigned long long v = 0;
    int done = (lane < GROUPS) ? 0 : 1;
    while (!__all(done)) {
      if (!done) {
        v = __hip_atomic_load(&line[lane], __ATOMIC_RELAXED,
                              __HIP_MEMORY_SCOPE_AGENT);
        done = (((uint32_t)(v >> TAG_SHIFT) & TAG_MASK) == tag);
      }
      if (!__all(done)) __builtin_amdgcn_s_sleep(1);
    }
    uint32_t fhi = (uint32_t)(v >> 32);
    const uint32_t fdb = wave_max_bcast(fhi);
    const uint32_t fmk = wave_max_bcast((fhi == fdb) ? ((uint32_t)v & IDX_MASK) : 0u);

    // ---- winner index + coords (scalar-path uniform load) ----
    cur = __builtin_amdgcn_readfirstlane((int)((~fmk) & IDX_MASK));
    const float* wp = pb + (size_t)cur * 3;
    cx = wp[0]; cy = wp[1]; cz = wp[2];
  }
}

extern "C" void kernel_launch(void* const* d_in, const int* in_sizes, int n_in,
                              void* d_out, int out_size, void* d_ws, size_t ws_size,
                              hipStream_t stream) {
  const float* points = (const float*)d_in[0];
  const int* nsamples = (const int*)d_in[1];
  // d_in[2] = kd_depth: acceleration parameter only; math identical. Ignored.

  const int P = in_sizes[0] / (BATCHES * 3);   // 131072

  uint64_t* cand = (uint64_t*)d_ws;   // [32][2][16 u64] = 8KB

  hipLaunchKernelGGL(init_ws_kernel, dim3(1), dim3(BATCHES * 2 * LINE_U64),
                     0, stream, cand);

  hipLaunchKernelGGL(fps_kernel, dim3(GROUPS * BATCHES), dim3(THREADS), 0,
                     stream, points, nsamples, (float*)d_out, cand, P);
}